// Round 2
// baseline (1635.281 us; speedup 1.0000x reference)
//
#include <hip/hip_runtime.h>
#include <math.h>

// y = LayerNorm( irfft(rfft(x, axis=S, ortho) * w, ortho) + x ), B=32 S=2048 H=1024 fp32.
// Identities: residual folded into weight (w+1); ortho norms folded as 1/2048 into weight.
// Per FFT (one channel PAIR, two-for-one packing): 2048 = 16 x 16 x 8.
//   128 threads x 16 complex regs. Stage1: 16-pt DFT in regs (+twiddle by recurrence),
//   LDS transpose, Stage2: 16-pt DFT in regs (+twiddle), Stage3: 8-pt DFT across 8-lane
//   groups via shfl_xor (no LDS/barrier). Spectrum lands in NATURAL k order.
//   Spectral multiply fused into inverse's first read (Hermitian pair read inline).
//   Inverse = conj(FWD(conj(V))) -- reuses identical forward code path.

#define C8f  0.70710678118654752f   // cos(pi/4)
#define SIN1 0.38268343236508977f   // sin(pi/8)
#define COS1 0.92387953251128674f   // cos(pi/8)

#define SW4(i) ((i) ^ ((((i) >> 8) & 7) << 3))   // fold bits 8..10 into bank nibble

static constexpr int BR4[16] = {0,8,4,12,2,10,6,14,1,9,5,13,3,11,7,15};

__device__ __forceinline__ float2 cadd(float2 a, float2 b){ return make_float2(a.x+b.x, a.y+b.y); }
__device__ __forceinline__ float2 csub(float2 a, float2 b){ return make_float2(a.x-b.x, a.y-b.y); }
__device__ __forceinline__ float2 cmul(float2 a, float2 b){ return make_float2(a.x*b.x - a.y*b.y, a.x*b.y + a.y*b.x); }

// 16-point DIF FFT, e^{-2pi i/16} twiddles, natural input, output at reg p = X[BR4[p]].
__device__ __forceinline__ void dft16_fwd(float2* r){
  const float WR[8] = {1.f,  COS1,  C8f,  SIN1, 0.f, -SIN1, -C8f, -COS1};
  const float WI[8] = {0.f, -SIN1, -C8f, -COS1, -1.f, -COS1, -C8f, -SIN1};
  #pragma unroll
  for (int m = 0; m < 8; ++m){
    float2 u = r[m], v = r[m+8];
    r[m] = cadd(u, v);
    float2 d = csub(u, v);
    r[m+8] = make_float2(d.x*WR[m] - d.y*WI[m], d.x*WI[m] + d.y*WR[m]);
  }
  #pragma unroll
  for (int h = 0; h < 16; h += 8){
    #pragma unroll
    for (int m = 0; m < 4; ++m){
      float2 u = r[h+m], v = r[h+m+4];
      r[h+m] = cadd(u, v);
      float2 d = csub(u, v);
      r[h+m+4] = make_float2(d.x*WR[2*m] - d.y*WI[2*m], d.x*WI[2*m] + d.y*WR[2*m]);
    }
  }
  #pragma unroll
  for (int h = 0; h < 16; h += 4){
    { float2 u=r[h],   v=r[h+2]; r[h]  =cadd(u,v); r[h+2]=csub(u,v); }
    { float2 u=r[h+1], v=r[h+3]; float2 d=csub(u,v); r[h+1]=cadd(u,v); r[h+3]=make_float2(d.y, -d.x); } // *(-i)
  }
  #pragma unroll
  for (int h = 0; h < 16; h += 2){
    float2 u=r[h], v=r[h+1]; r[h]=cadd(u,v); r[h+1]=csub(u,v);
  }
}

// r[BR4[k]] *= step^k for k=1..15 (recurrence).
__device__ __forceinline__ void twiddle_apply(float2* r, float2 step){
  float2 tw = step;
  #pragma unroll
  for (int k = 1; k < 16; ++k){
    int p = BR4[k];
    r[p] = cmul(r[p], tw);
    if (k < 15) tw = cmul(tw, step);
  }
}

__device__ __forceinline__ float2 shflx(float2 v, int m){
  return make_float2(__shfl_xor(v.x, m, 64), __shfl_xor(v.y, m, 64));
}

__device__ __forceinline__ float2 fetchW(const float2* __restrict__ wT,
                                         const float2* __restrict__ cw,
                                         int useT, int h, int k){
  if (useT) return wT[(size_t)h * 1025 + k];
  float2 w = cw[(size_t)k * 1024 + h];
  const float inv = 1.0f / 2048.0f;
  return make_float2((w.x + 1.0f) * inv, w.y * inv);
}

// weight prep: wT[h][k] = (cw[k][h] + 1) / 2048 (residual + ortho-norm folded)
__global__ void prep_w_kernel(const float2* __restrict__ cw, float2* __restrict__ wT){
  __shared__ float2 tile[32][33];
  int k0 = blockIdx.x * 32, h0 = blockIdx.y * 32;
  int tx = threadIdx.x, ty = threadIdx.y;   // 32 x 8
  #pragma unroll
  for (int r = 0; r < 4; ++r){
    int k = k0 + ty + 8 * r;
    if (k < 1025) tile[ty + 8*r][tx] = cw[(size_t)k * 1024 + (h0 + tx)];
  }
  __syncthreads();
  const float inv = 1.0f / 2048.0f;
  #pragma unroll
  for (int r = 0; r < 4; ++r){
    int h = h0 + ty + 8 * r;
    int k = k0 + tx;
    if (k < 1025){
      float2 w = tile[tx][ty + 8*r];
      wT[(size_t)h * 1025 + k] = make_float2((w.x + 1.0f) * inv, w.y * inv);
    }
  }
}

__global__ __launch_bounds__(512, 4) void fft_filter_kernel(
    const float2* __restrict__ x,    // [B,2048,512] float2 (adjacent h pairs)
    const float2* __restrict__ cw,
    const float2* __restrict__ wT,
    int useT,
    float2* __restrict__ out){
  __shared__ float2 lds[4][2048];    // 64 KB, one 2048-pt FFT per plane
  const int t  = threadIdx.x;
  const int bx = blockIdx.x;
  const int b  = bx >> 7;            // 128 WGs per batch
  const int pg = bx & 127;           // pair-group: pairs 4*pg .. 4*pg+3
  const int f  = t >> 7;             // FFT index 0..3
  const int j  = t & 127;            // worker within FFT
  float2* A = lds[f];

  // ---- load bounce: global (32B segments) -> LDS natural-s ----
  {
    const int p4 = t & 3, srow = t >> 2;
    const size_t base = ((size_t)b * 2048) * 512 + (size_t)(pg * 4 + p4);
    #pragma unroll
    for (int it = 0; it < 16; ++it){
      int s = srow + (it << 7);
      lds[p4][SW4(s)] = x[base + (size_t)s * 512];
    }
  }
  __syncthreads();

  float2 r[16];
  const int k1 = j >> 3, bb = j & 7;
  const int rb = ((bb & 1) << 2) | (bb & 2) | ((bb & 4) >> 2);  // br3(bb)

  // per-thread shuffle-stage twiddles (forward, e^{-i})
  const float2 w8c = make_float2((bb & 1) ? ((bb & 2) ? -C8f : C8f) : ((bb & 2) ? 0.f : 1.f),
                                 (bb & 1) ? -C8f : ((bb & 2) ? -1.f : 0.f));
  const float2 w4c = (bb & 1) ? make_float2(0.f, -1.f) : make_float2(1.f, 0.f);
  const bool h4 = (bb & 4), h2 = (bb & 2), h1 = (bb & 1);

  float sn, cs;
  __sincosf(-6.2831853071795864769f * (float)j * (1.0f / 2048.0f), &sn, &cs);
  const float2 stepJ = make_float2(cs, sn);   // e^{-2pi i j/2048}
  __sincosf(-6.2831853071795864769f * (float)bb * (1.0f / 128.0f), &sn, &cs);
  const float2 stepB = make_float2(cs, sn);   // e^{-2pi i b/128}

  // ---- forward: stage 1 (over n1) ----
  #pragma unroll
  for (int n1 = 0; n1 < 16; ++n1) r[n1] = A[SW4(128 * n1 + j)];
  dft16_fwd(r);
  twiddle_apply(r, stepJ);
  __syncthreads();                      // reads of natural-s done
  #pragma unroll
  for (int p = 0; p < 16; ++p){         // write [k1][n2] with per-row swizzle
    int kk1 = BR4[p];
    A[128 * kk1 + (j ^ ((kk1 & 1) << 3))] = r[p];
  }
  __syncthreads();

  // ---- forward: stage 2 (over a) ----
  #pragma unroll
  for (int a = 0; a < 16; ++a)
    r[a] = A[128 * k1 + (((a << 3) + bb) ^ ((k1 & 1) << 3))];
  dft16_fwd(r);
  twiddle_apply(r, stepB);

  // ---- forward: stage 3, 8-pt DIF over b via shuffles ----
  #pragma unroll
  for (int p = 0; p < 16; ++p){
    float2 z = r[p];
    float2 tt = shflx(z, 4);
    float2 a1 = h4 ? csub(tt, z) : cadd(z, tt);
    z = h4 ? cmul(a1, w8c) : a1;
    tt = shflx(z, 2);
    a1 = h2 ? csub(tt, z) : cadd(z, tt);
    z = h2 ? cmul(a1, w4c) : a1;
    tt = shflx(z, 1);
    r[p] = h1 ? csub(tt, z) : cadd(z, tt);
  }
  __syncthreads();                      // stage-2 LDS reads done
  #pragma unroll
  for (int p = 0; p < 16; ++p){         // write natural-k spectrum
    int c = BR4[p];
    int k = k1 + (c << 4) + (rb << 8);
    A[SW4(k)] = r[p];
  }
  __syncthreads();

  // ---- fused spectral multiply + inverse first read (conj for inverse-via-forward) ----
  const int hA = (pg << 3) + (f << 1);
  #pragma unroll
  for (int q = 0; q < 16; ++q){
    int kk = (q << 7) + j;
    float2 V;
    if (kk == 0){
      float2 X0 = A[SW4(0)];
      float2 wa = fetchW(wT, cw, useT, hA, 0);
      float2 wb = fetchW(wT, cw, useT, hA + 1, 0);
      V = make_float2(X0.x * wa.x, X0.y * wb.x);
    } else if (kk == 1024){
      float2 Xn = A[SW4(1024)];
      float2 wa = fetchW(wT, cw, useT, hA, 1024);
      float2 wb = fetchW(wT, cw, useT, hA + 1, 1024);
      V = make_float2(Xn.x * wa.x, Xn.y * wb.x);
    } else {
      int k = (kk < 1024) ? kk : 2048 - kk;
      float2 Z1 = A[SW4(k)];
      float2 Z2 = A[SW4(2048 - k)];
      float2 wa = fetchW(wT, cw, useT, hA, k);
      float2 wb = fetchW(wT, cw, useT, hA + 1, k);
      float2 Xa = make_float2(0.5f*(Z1.x + Z2.x), 0.5f*(Z1.y - Z2.y));
      float2 Xb = make_float2(0.5f*(Z1.y + Z2.y), 0.5f*(Z2.x - Z1.x));
      float2 Ya = cmul(Xa, wa);
      float2 Yb = cmul(Xb, wb);
      V = (kk < 1024) ? make_float2(Ya.x - Yb.y, Ya.y + Yb.x)
                      : make_float2(Ya.x + Yb.y, Yb.x - Ya.y);
    }
    r[q] = make_float2(V.x, -V.y);      // conj
  }

  // ---- inverse chain = forward machinery on conj(V) ----
  dft16_fwd(r);
  twiddle_apply(r, stepJ);
  __syncthreads();                      // spectral reads done
  #pragma unroll
  for (int p = 0; p < 16; ++p){
    int s1 = BR4[p];
    A[128 * s1 + (j ^ ((s1 & 1) << 3))] = r[p];
  }
  __syncthreads();
  #pragma unroll
  for (int a = 0; a < 16; ++a)
    r[a] = A[128 * k1 + (((a << 3) + bb) ^ ((k1 & 1) << 3))];
  dft16_fwd(r);
  twiddle_apply(r, stepB);
  #pragma unroll
  for (int p = 0; p < 16; ++p){
    float2 z = r[p];
    float2 tt = shflx(z, 4);
    float2 a1 = h4 ? csub(tt, z) : cadd(z, tt);
    z = h4 ? cmul(a1, w8c) : a1;
    tt = shflx(z, 2);
    a1 = h2 ? csub(tt, z) : cadd(z, tt);
    z = h2 ? cmul(a1, w4c) : a1;
    tt = shflx(z, 1);
    r[p] = h1 ? csub(tt, z) : cadd(z, tt);
  }
  __syncthreads();                      // stage-2' reads done
  #pragma unroll
  for (int p = 0; p < 16; ++p){         // write natural-s, conj back
    int g = BR4[p];
    int s = k1 + (g << 4) + (rb << 8);
    A[SW4(s)] = make_float2(r[p].x, -r[p].y);
  }
  __syncthreads();

  // ---- store bounce: LDS natural-s -> global (32B segments) ----
  {
    const int p4 = t & 3, srow = t >> 2;
    const size_t base = ((size_t)b * 2048) * 512 + (size_t)(pg * 4 + p4);
    #pragma unroll
    for (int it = 0; it < 16; ++it){
      int s = srow + (it << 7);
      out[base + (size_t)s * 512] = lds[p4][SW4(s)];
    }
  }
}

// ---- LayerNorm over H=1024: one wave per row, no barriers, no LDS ----
__global__ __launch_bounds__(256) void ln_kernel(float* __restrict__ io,
                                                 const float* __restrict__ gma,
                                                 const float* __restrict__ bta){
  const int t = threadIdx.x;
  const int lane = t & 63;
  const size_t row = (size_t)blockIdx.x * 4 + (t >> 6);
  float4* r4 = (float4*)io + row * 256;
  const float4* g4 = (const float4*)gma;
  const float4* b4 = (const float4*)bta;
  float4 v[4];
  #pragma unroll
  for (int i = 0; i < 4; ++i) v[i] = r4[lane + 64 * i];
  float s1 = 0.f, s2 = 0.f;
  #pragma unroll
  for (int i = 0; i < 4; ++i){
    s1 += v[i].x + v[i].y + v[i].z + v[i].w;
    s2 += v[i].x*v[i].x + v[i].y*v[i].y + v[i].z*v[i].z + v[i].w*v[i].w;
  }
  #pragma unroll
  for (int m = 32; m >= 1; m >>= 1){
    s1 += __shfl_xor(s1, m, 64);
    s2 += __shfl_xor(s2, m, 64);
  }
  const float mean = s1 * (1.0f / 1024.0f);
  const float var  = s2 * (1.0f / 1024.0f) - mean * mean;
  const float rstd = rsqrtf(fmaxf(var, 0.0f) + 1e-12f);
  #pragma unroll
  for (int i = 0; i < 4; ++i){
    float4 gv = g4[lane + 64 * i], bv = b4[lane + 64 * i], o;
    o.x = (v[i].x - mean) * rstd * gv.x + bv.x;
    o.y = (v[i].y - mean) * rstd * gv.y + bv.y;
    o.z = (v[i].z - mean) * rstd * gv.z + bv.z;
    o.w = (v[i].w - mean) * rstd * gv.w + bv.w;
    r4[lane + 64 * i] = o;
  }
}

extern "C" void kernel_launch(void* const* d_in, const int* in_sizes, int n_in,
                              void* d_out, int out_size, void* d_ws, size_t ws_size,
                              hipStream_t stream){
  const float2* x2  = (const float2*)d_in[0];
  const float2* cw2 = (const float2*)d_in[1];
  const float*  gma = (const float*)d_in[2];
  const float*  bta = (const float*)d_in[3];
  float2* out2 = (float2*)d_out;
  float*  outf = (float*)d_out;

  const int Bn = in_sizes[0] / (2048 * 1024);   // 32

  const size_t needW = (size_t)1025 * 1024 * sizeof(float2);
  const int useT = (ws_size >= needW) ? 1 : 0;
  float2* wT = (float2*)d_ws;

  if (useT){
    hipLaunchKernelGGL(prep_w_kernel, dim3(33, 32), dim3(32, 8), 0, stream, cw2, wT);
  }
  hipLaunchKernelGGL(fft_filter_kernel, dim3(Bn * 128), dim3(512), 0, stream,
                     x2, cw2, wT, useT, out2);
  hipLaunchKernelGGL(ln_kernel, dim3(Bn * 512), dim3(256), 0, stream,
                     outf, gma, bta);
}